// Round 9
// baseline (966.504 us; speedup 1.0000x reference)
//
#include <hip/hip_runtime.h>
#include <math.h>

// WfcNN: B=262144.
//   h1 = tanh(x @ W0 + b0)            (B,128)
//   h2 = tanh(h1 @ W1 + b1)           (B,64)
//   g  = tanh(h2 . Wa[eid] + ba[eid]) (B,32)
//   psi= g . Wb[eid] + bb[eid]        (B,2) ; out = psi / sqrt(|psi|^2+1e-6)
//
// Round 18: FULL single-kernel fusion (memset + 1 kernel).
//  R17 post-mortem: fused prologue passed (spin-barrier pattern VALIDATED on
//  this harness) and wfc hit its proven 56us, but non-wfc stayed ~102us with
//  only memset+1 prologue kernel -> per-dispatch-cost theory refuted. wfc is
//  stable ~56us; non-wfc (60..102us) never correlates with prologue code.
//  Decisive experiment: ONE kernel. total - kernel_dur = true harness floor.
//  Grid 2048x64 (8 blocks/CU = the proven MLP residency regime; prologue
//  blocks 0..286 dispatched first, trivially co-resident -> deadlock-free):
//   blk 0..255:  hist (16 samp/thread, rank in regs) -> padded global
//                reservation (R13-proven) -> spin sync1==256 -> esrt scan ->
//                register scatter to perm -> signal sync2.
//   blk 256..286: weight split-pack (W1, Wa[e]) -> signal sync2.
//   ALL: spin sync2==287 -> load etot -> grid-stride segments (reversed so
//        extras land on idle blocks) -> PROVEN MLP body verbatim.
//  perm read via agent-scope atomic loads (cross-XCD within-kernel); weights
//  by release-fence + acquire-flag (R17-validated).
// Cooperative-launch API FAILED in R8 -- this uses resident spin instead.

#define THREADS 64        // 1 wave per block
#define GRID 2048         // 8 blocks/CU on 256 CUs
#define NE 30
#define NHIST 256         // hist blocks; 1024 samples each
#define NPACK 31          // 1 W1 block + 30 Wa blocks
#define ETS 16            // etot stride: one counter per 64B line
#define SA 67             // u32 row stride for [k][sample] staging (64+3)
#define SG 36             // f32 row stride for [sample][h] g staging

typedef short bf16x8 __attribute__((ext_vector_type(8)));
typedef float f32x4 __attribute__((ext_vector_type(4)));

__device__ __forceinline__ int expert_id(int nn, int ll, int mm) {
    return ((nn - 1) * nn * (2 * nn - 1)) / 6 + ll * ll + ll + mm;
}

// tanh(v) = 1 - 2/(exp2(2*log2e*v)+1); saturates correctly, no clamp.
__device__ __forceinline__ float fast_tanh(float v) {
    float e = __builtin_exp2f(v * 2.885390082f);
    return fmaf(-2.0f, __builtin_amdgcn_rcpf(e + 1.0f), 1.0f);
}

__device__ __forceinline__ unsigned int f2b(float f) {   // f32 -> bf16 RNE
    unsigned int u = __float_as_uint(f);
    return (u + 0x7fffu + ((u >> 16) & 1u)) >> 16;
}
__device__ __forceinline__ float b2f(unsigned int b) {
    return __uint_as_float(b << 16);
}
// runtime split: RNE hi, truncated lo; packed (lo16<<16)|hi16
__device__ __forceinline__ unsigned int packsplit(float v) {
    const unsigned int hb = f2b(v);
    const float lo = v - b2f(hb);
    return (__float_as_uint(lo) & 0xffff0000u) | hb;
}

union U8 { unsigned int u[4]; bf16x8 v; };
// packed words -> hi-plane / lo-plane bf16x8 (bit-identical to shift/mask form)
__device__ __forceinline__ void unpack8(const unsigned int* w, bf16x8& hi, bf16x8& lo) {
    U8 H, L;
#pragma unroll
    for (int i = 0; i < 4; ++i) {
        H.u[i] = __builtin_amdgcn_perm(w[2 * i + 1], w[2 * i], 0x05040100u);
        L.u[i] = __builtin_amdgcn_perm(w[2 * i + 1], w[2 * i], 0x07060302u);
    }
    hi = H.v; lo = L.v;
}

// ---- THE kernel: hist + sort + pack + barrier + fused MLP ----
__global__ __launch_bounds__(THREADS, 4) void mono_kernel(
    const float* __restrict__ x,
    const int* __restrict__ nq, const int* __restrict__ lq, const int* __restrict__ mq,
    int* __restrict__ sync1, int* __restrict__ sync2,
    int* __restrict__ etot, int* __restrict__ perm,
    const float* __restrict__ W0, const float* __restrict__ b0,
    const float* __restrict__ W1g,
    unsigned short* __restrict__ W1fhS, unsigned short* __restrict__ W1flS,
    const float* __restrict__ Wag,
    unsigned short* __restrict__ WafhS, unsigned short* __restrict__ WaflS,
    const float* __restrict__ b1, const float* __restrict__ ba,
    const float* __restrict__ Wb, const float* __restrict__ bb,
    float* __restrict__ out)
{
    __shared__ unsigned int sbuf[2304];      // 9216 B staging (MLP phase)
    __shared__ int etl[NE], bbL[NE], esrtL[NE], h[NE];

    const int tid = threadIdx.x;
    const int bx = blockIdx.x;

    if (bx < NHIST) {
        // ---------- hist + reservation + scatter ----------
        if (tid < NE) h[tid] = 0;
        __syncthreads();
        const int base = bx << 10;           // 1024 samples
        int pk[16];
#pragma unroll
        for (int j = 0; j < 16; ++j) {
            const int i = base + (j << 6) + tid;
            const int e = expert_id(nq[i], lq[i], mq[i]);
            const int r = atomicAdd(&h[e], 1);           // LDS
            pk[j] = (r << 5) | e;                        // r < 1024, e < 30
        }
        __syncthreads();
        if (tid < NE)                                    // padded global reservation
            bbL[tid] = atomicAdd(&etot[tid * ETS], h[tid]);
        if (tid == 0) {
            __threadfence();
            atomicAdd(sync1, 1);
            while (__hip_atomic_load(sync1, __ATOMIC_ACQUIRE,
                                     __HIP_MEMORY_SCOPE_AGENT) < NHIST)
                __builtin_amdgcn_s_sleep(8);
        }
        __syncthreads();
        if (tid < NE)
            etl[tid] = __hip_atomic_load(&etot[tid * ETS], __ATOMIC_RELAXED,
                                         __HIP_MEMORY_SCOPE_AGENT);
        __syncthreads();
        if (tid == 0) {
            int es = 0;
            for (int e = 0; e < NE; ++e) { esrtL[e] = es; es += etl[e]; }
        }
        __syncthreads();
#pragma unroll
        for (int j = 0; j < 16; ++j) {
            const int e = pk[j] & 31;
            perm[esrtL[e] + bbL[e] + (pk[j] >> 5)] = base + (j << 6) + tid;
        }
        if (tid == 0) { __threadfence(); atomicAdd(sync2, 1); }
    } else if (bx == NHIST) {
        // ---------- W1 (128,64) -> hi/lo planes (rec=((c*4+nt)*4+qd)*16+l16) ----------
        for (int i = tid; i < 8192; i += THREADS) {
            const int j = i & 7, s = (i >> 3) & 15, q = (i >> 7) & 3;
            const int nt = (i >> 9) & 3, c = i >> 11;
            const int k = c * 32 + q * 8 + j, n = nt * 16 + s;
            const float w = W1g[k * 64 + n];
            const unsigned int hb = f2b(w);
            W1fhS[i] = (unsigned short)hb;
            W1flS[i] = (unsigned short)f2b(w - b2f(hb));
        }
        if (tid == 0) { __threadfence(); atomicAdd(sync2, 1); }
    } else if (bx < NHIST + NPACK) {
        // ---------- Wa[e] (64,32) -> hi/lo planes (rec=((c2*2+nt2)*4+qd)*16+l16) ----------
        const int e = bx - NHIST - 1;
        for (int i = tid; i < 2048; i += THREADS) {
            const int j = i & 7, s = (i >> 3) & 15, q = (i >> 7) & 3;
            const int nt2 = (i >> 9) & 1, c2 = (i >> 10) & 1;
            const int d = c2 * 32 + q * 8 + j, hh = nt2 * 16 + s;
            const float w = Wag[e * 2048 + d * 32 + hh];
            const unsigned int hb = f2b(w);
            WafhS[e * 2048 + i] = (unsigned short)hb;
            WaflS[e * 2048 + i] = (unsigned short)f2b(w - b2f(hb));
        }
        if (tid == 0) { __threadfence(); atomicAdd(sync2, 1); }
    }

    // ---------- barrier: prologue complete ----------
    if (tid == 0) {
        while (__hip_atomic_load(sync2, __ATOMIC_ACQUIRE,
                                 __HIP_MEMORY_SCOPE_AGENT) < NHIST + NPACK)
            __builtin_amdgcn_s_sleep(16);
    }
    __syncthreads();
    if (tid < NE)
        etl[tid] = __hip_atomic_load(&etot[tid * ETS], __ATOMIC_RELAXED,
                                     __HIP_MEMORY_SCOPE_AGENT);
    __syncthreads();

    const bf16x8* __restrict__ W1fh = (const bf16x8*)W1fhS;
    const bf16x8* __restrict__ W1fl = (const bf16x8*)W1flS;
    const bf16x8* __restrict__ Wafh = (const bf16x8*)WafhS;
    const bf16x8* __restrict__ Wafl = (const bf16x8*)WaflS;

    const int lane = tid & 63;
    const int wv   = 0;
    const int qd   = lane >> 4;
    const int l16  = lane & 15;
    const int vbx  = (GRID - 1) - bx;        // reversed: extras -> idle blocks

    for (int gid = vbx; ; gid += GRID) {
        // derive (eid, start, cnt): uniform 30-iter scan over LDS etl
        int eid = -1, start = 0, cnt = 0;
        {
            int cum = 0, es = 0;
#pragma unroll 1
            for (int e = 0; e < NE; ++e) {
                const int t = etl[e];
                const int nb = (t + 63) >> 6;
                if (gid < cum + nb) {
                    const int seg = gid - cum;
                    eid = e; start = es + (seg << 6); cnt = min(64, t - (seg << 6));
                    break;
                }
                cum += nb; es += t;
            }
        }
        if (eid < 0) break;
        eid = __builtin_amdgcn_readfirstlane(eid);

        const bool valid = tid < cnt;
        const int idx = __hip_atomic_load(&perm[start + (valid ? tid : 0)],
                                          __ATOMIC_RELAXED, __HIP_MEMORY_SCOPE_AGENT);

        const float x0 = x[idx * 3 + 0];
        const float x1 = x[idx * 3 + 1];
        const float x2 = x[idx * 3 + 2];

        // ---- layer 2 accumulators, init b1 (C layout: col = l16) ----
        f32x4 acc[4][4];
#pragma unroll
        for (int nt = 0; nt < 4; ++nt) {
            const float bv = b1[nt * 16 + l16];
#pragma unroll
            for (int mt = 0; mt < 4; ++mt) {
                f32x4 c; c[0] = bv; c[1] = bv; c[2] = bv; c[3] = bv;
                acc[mt][nt] = c;
            }
        }

        // ---- layer-2 GEMM: 4 K-chunks of 32 ----
        for (int c = 0; c < 4; ++c) {
            __syncthreads();                 // also guards inter-segment sbuf reuse
#pragma unroll
            for (int kk = 0; kk < 32; ++kk) {
                const int k = c * 32 + kk;
                const float pre = fmaf(x0, W0[k], fmaf(x1, W0[128 + k], fmaf(x2, W0[256 + k], b0[k])));
                sbuf[kk * SA + tid] = packsplit(fast_tanh(pre));
            }
            __syncthreads();

            bf16x8 Bhi[4], Blo[4];
#pragma unroll
            for (int nt = 0; nt < 4; ++nt) {
                const int rec = (c * 4 + nt) * 64 + qd * 16 + l16;
                Bhi[nt] = W1fh[rec];
                Blo[nt] = W1fl[rec];
            }
#pragma unroll
            for (int mt = 0; mt < 4; ++mt) {
                unsigned int a[8];
                const int mrow = wv * 64 + mt * 16 + l16;
#pragma unroll
                for (int j = 0; j < 8; ++j) a[j] = sbuf[(qd * 8 + j) * SA + mrow];
                bf16x8 Ahi, Alo;
                unpack8(a, Ahi, Alo);
#pragma unroll
                for (int nt = 0; nt < 4; ++nt) {
                    acc[mt][nt] = __builtin_amdgcn_mfma_f32_16x16x32_bf16(Ahi, Bhi[nt], acc[mt][nt], 0, 0, 0);
                    acc[mt][nt] = __builtin_amdgcn_mfma_f32_16x16x32_bf16(Ahi, Blo[nt], acc[mt][nt], 0, 0, 0);
                    acc[mt][nt] = __builtin_amdgcn_mfma_f32_16x16x32_bf16(Alo, Bhi[nt], acc[mt][nt], 0, 0, 0);
                }
            }
        }

        // ---- expert-A accumulators, init ba ----
        f32x4 acc2[4][2];
#pragma unroll
        for (int nt2 = 0; nt2 < 2; ++nt2) {
            const float bv = ba[(eid << 5) + nt2 * 16 + l16];
#pragma unroll
            for (int mt = 0; mt < 4; ++mt) {
                f32x4 c; c[0] = bv; c[1] = bv; c[2] = bv; c[3] = bv;
                acc2[mt][nt2] = c;
            }
        }

        // ---- expert-A GEMM: h2 = tanh(acc) restaged [d][sample]; 2 K-chunks ----
        const bf16x8* __restrict__ waeh = Wafh + (eid << 8);
        const bf16x8* __restrict__ wael = Wafl + (eid << 8);
        for (int c2 = 0; c2 < 2; ++c2) {
            __syncthreads();
#pragma unroll
            for (int mt = 0; mt < 4; ++mt) {
#pragma unroll
                for (int ntl = 0; ntl < 2; ++ntl) {
#pragma unroll
                    for (int r = 0; r < 4; ++r) {
                        const float h2 = fast_tanh(acc[mt][c2 * 2 + ntl][r]);
                        const int dl  = ntl * 16 + l16;
                        const int row = wv * 64 + mt * 16 + qd * 4 + r;
                        sbuf[dl * SA + row] = packsplit(h2);
                    }
                }
            }
            __syncthreads();

            bf16x8 B2hi[2], B2lo[2];
#pragma unroll
            for (int nt2 = 0; nt2 < 2; ++nt2) {
                const int rec = (c2 * 2 + nt2) * 64 + qd * 16 + l16;
                B2hi[nt2] = waeh[rec];
                B2lo[nt2] = wael[rec];
            }
#pragma unroll
            for (int mt = 0; mt < 4; ++mt) {
                unsigned int a[8];
                const int mrow = wv * 64 + mt * 16 + l16;
#pragma unroll
                for (int j = 0; j < 8; ++j) a[j] = sbuf[(qd * 8 + j) * SA + mrow];
                bf16x8 Ahi, Alo;
                unpack8(a, Ahi, Alo);
#pragma unroll
                for (int nt2 = 0; nt2 < 2; ++nt2) {
                    acc2[mt][nt2] = __builtin_amdgcn_mfma_f32_16x16x32_bf16(Ahi, B2hi[nt2], acc2[mt][nt2], 0, 0, 0);
                    acc2[mt][nt2] = __builtin_amdgcn_mfma_f32_16x16x32_bf16(Ahi, B2lo[nt2], acc2[mt][nt2], 0, 0, 0);
                    acc2[mt][nt2] = __builtin_amdgcn_mfma_f32_16x16x32_bf16(Alo, B2hi[nt2], acc2[mt][nt2], 0, 0, 0);
                }
            }
        }

        // ---- g = tanh(acc2) staged [sample][h], expert-B per-thread ----
        __syncthreads();
        float* g2 = (float*)sbuf;
#pragma unroll
        for (int mt = 0; mt < 4; ++mt) {
#pragma unroll
            for (int nt2 = 0; nt2 < 2; ++nt2) {
#pragma unroll
                for (int r = 0; r < 4; ++r) {
                    const int row = wv * 64 + mt * 16 + qd * 4 + r;
                    g2[row * SG + nt2 * 16 + l16] = fast_tanh(acc2[mt][nt2][r]);
                }
            }
        }
        __syncthreads();

        float gv[32];
        {
            const float4* grow = (const float4*)(g2 + tid * SG);
#pragma unroll
            for (int i = 0; i < 8; ++i) {
                float4 v = grow[i];
                gv[4 * i + 0] = v.x; gv[4 * i + 1] = v.y;
                gv[4 * i + 2] = v.z; gv[4 * i + 3] = v.w;
            }
        }

        const float* __restrict__ wbe = Wb + (eid << 6);
        float p0 = bb[2 * eid], p1 = bb[2 * eid + 1];
#pragma unroll
        for (int hh = 0; hh < 32; ++hh) {
            p0 = fmaf(gv[hh], wbe[2 * hh + 0], p0);
            p1 = fmaf(gv[hh], wbe[2 * hh + 1], p1);
        }

        const float s = fmaf(p0, p0, fmaf(p1, p1, 1e-6f));
        const float inv = 1.0f / sqrtf(s);
        if (valid) {
            float2 o; o.x = p0 * inv; o.y = p1 * inv;
            ((float2*)out)[idx] = o;
        }
    }
}

extern "C" void kernel_launch(void* const* d_in, const int* in_sizes, int n_in,
                              void* d_out, int out_size, void* d_ws, size_t ws_size,
                              hipStream_t stream) {
    const float* x  = (const float*)d_in[0];
    const int*   n  = (const int*)d_in[1];
    const int*   l  = (const int*)d_in[2];
    const int*   m  = (const int*)d_in[3];
    const float* W0 = (const float*)d_in[4];
    const float* b0 = (const float*)d_in[5];
    const float* W1 = (const float*)d_in[6];
    const float* b1 = (const float*)d_in[7];
    const float* Wa = (const float*)d_in[8];
    const float* ba = (const float*)d_in[9];
    const float* Wb = (const float*)d_in[10];
    const float* bb = (const float*)d_in[11];
    float* out = (float*)d_out;

    const int B = in_sizes[1];   // 262144
    (void)B;

    // workspace layout (all segments 16B aligned)
    int*            sync1 = (int*)d_ws;                      // [0]
    int*            sync2 = sync1 + 16;                      // [16] separate line
    int*            etot  = sync1 + 32;                      // NE*ETS = 480
    int*            perm  = sync1 + 512;                     // B   (zero region = 2048 B)
    unsigned short* W1fh  = (unsigned short*)(perm + 262144);// 8192 u16
    unsigned short* W1fl  = W1fh + 8192;                     // 8192 u16
    unsigned short* Wafh  = W1fl + 8192;                     // 30*2048 u16
    unsigned short* Wafl  = Wafh + NE * 2048;                // 30*2048 u16

    hipMemsetAsync(sync1, 0, 2048, stream);   // sync1, sync2, etot
    mono_kernel<<<GRID, THREADS, 0, stream>>>(
        x, n, l, m, sync1, sync2, etot, perm,
        W0, b0, W1, W1fh, W1fl, Wa, Wafh, Wafl,
        b1, ba, Wb, bb, out);
}

// Round 10
// 142.309 us; speedup vs baseline: 6.7916x; 6.7916x over previous
//
#include <hip/hip_runtime.h>
#include <math.h>

// WfcNN: B=262144.
//   h1 = tanh(x @ W0 + b0)            (B,128)
//   h2 = tanh(h1 @ W1 + b1)           (B,64)
//   g  = tanh(h2 . Wa[eid] + ba[eid]) (B,32)
//   psi= g . Wb[eid] + bb[eid]        (B,2) ; out = psi / sqrt(|psi|^2+1e-6)
//
// Round 19: baseline prologue + proven 64-thread wfc (the one combination
// never measured together).
//  R18 post-mortem: mono-kernel 922us -- 2048-wave spin barrier convoys at
//  the coherence point (~890us stall; VALUBusy*dur conserved). NEVER use
//  grid-wide spin barriers here. KEY MEASUREMENT: total - kernel_dur = 44us
//  with memset+1 kernel => harness floor ~44us. Fitting all rounds:
//  floor ~40-44, R0 prologue (HB=128 hist+scatter, unpadded etot) ~13-17us,
//  my heavier prologues 35-56us. wfc stable at ~56us (proven R10/R13/R17).
//  => this round: baseline hist/scatter/memset VERBATIM + 64-thread wfc
//  with in-kernel etot scan (R17-proven at 56.3us). Predicted ~116-126us.
// Cooperative fusion FAILED (R8); spin barriers FAIL (R18). Do not retry.

#define THREADS 64        // wfc block = 1 wave = 64 samples
#define NE 30
#define HB 128            // hist/scatter blocks (baseline-proven, ~13-17us)
#define MAXBLK 4126       // 262144/64 + 30 partial blocks
#define SA 67             // u32 row stride for [k][sample] staging (64+3)
#define SG 36             // f32 row stride for [sample][h] g staging

typedef short bf16x8 __attribute__((ext_vector_type(8)));
typedef float f32x4 __attribute__((ext_vector_type(4)));

__device__ __forceinline__ int expert_id(int nn, int ll, int mm) {
    return ((nn - 1) * nn * (2 * nn - 1)) / 6 + ll * ll + ll + mm;
}

// tanh(v) = 1 - 2/(exp2(2*log2e*v)+1); saturates correctly, no clamp.
__device__ __forceinline__ float fast_tanh(float v) {
    float e = __builtin_exp2f(v * 2.885390082f);
    return fmaf(-2.0f, __builtin_amdgcn_rcpf(e + 1.0f), 1.0f);
}

__device__ __forceinline__ unsigned int f2b(float f) {   // f32 -> bf16 RNE
    unsigned int u = __float_as_uint(f);
    return (u + 0x7fffu + ((u >> 16) & 1u)) >> 16;
}
__device__ __forceinline__ float b2f(unsigned int b) {
    return __uint_as_float(b << 16);
}
// runtime split: RNE hi, truncated lo; packed (lo16<<16)|hi16
__device__ __forceinline__ unsigned int packsplit(float v) {
    const unsigned int hb = f2b(v);
    const float lo = v - b2f(hb);
    return (__float_as_uint(lo) & 0xffff0000u) | hb;
}

union U8 { unsigned int u[4]; bf16x8 v; };
// packed words -> hi-plane / lo-plane bf16x8 (bit-identical to shift/mask form)
__device__ __forceinline__ void unpack8(const unsigned int* w, bf16x8& hi, bf16x8& lo) {
    U8 H, L;
#pragma unroll
    for (int i = 0; i < 4; ++i) {
        H.u[i] = __builtin_amdgcn_perm(w[2 * i + 1], w[2 * i], 0x05040100u);
        L.u[i] = __builtin_amdgcn_perm(w[2 * i + 1], w[2 * i], 0x07060302u);
    }
    hi = H.v; lo = L.v;
}

// ---- K1: hist + eid cache + bucket base reservation + weight splitting ----
// BASELINE VERBATIM (HB=128, unpadded etot; measured ~13-17us incl. K2).
__global__ void hist_pack_kernel(const int* __restrict__ nq, const int* __restrict__ lq,
                                 const int* __restrict__ mq,
                                 int* __restrict__ eids, int* __restrict__ etot,
                                 int* __restrict__ bbase,
                                 const float* __restrict__ W1,
                                 unsigned short* __restrict__ W1fh, unsigned short* __restrict__ W1fl,
                                 const float* __restrict__ Wa,
                                 unsigned short* __restrict__ Wafh, unsigned short* __restrict__ Wafl,
                                 int B) {
    const int tid = threadIdx.x;
    const int bx = blockIdx.x;
    if (bx < HB) {
        __shared__ int h[NE];
        if (tid < NE) h[tid] = 0;
        __syncthreads();
        const int per = B / HB, base = bx * per;
        for (int i = tid; i < per; i += blockDim.x) {
            const int e = expert_id(nq[base + i], lq[base + i], mq[base + i]);
            eids[base + i] = e;
            atomicAdd(&h[e], 1);
        }
        __syncthreads();
        if (tid < NE) bbase[bx * NE + tid] = atomicAdd(&etot[tid], h[tid]);
    } else if (bx == HB) {
        // W1 (128,64) -> hi/lo planes in B-frag order (rec=((c*4+nt)*4+qd)*16+l16)
        for (int i = tid; i < 8192; i += blockDim.x) {
            const int j = i & 7, s = (i >> 3) & 15, q = (i >> 7) & 3;
            const int nt = (i >> 9) & 3, c = i >> 11;
            const int k = c * 32 + q * 8 + j, n = nt * 16 + s;
            const float w = W1[k * 64 + n];
            const unsigned int hb = f2b(w);
            W1fh[i] = (unsigned short)hb;
            W1fl[i] = (unsigned short)f2b(w - b2f(hb));
        }
    } else {
        // Wa[e] (64,32) -> hi/lo planes (rec=((c2*2+nt2)*4+qd)*16+l16)
        const int e = bx - HB - 1;
        for (int i = tid; i < 2048; i += blockDim.x) {
            const int j = i & 7, s = (i >> 3) & 15, q = (i >> 7) & 3;
            const int nt2 = (i >> 9) & 1, c2 = (i >> 10) & 1;
            const int d = c2 * 32 + q * 8 + j, hh = nt2 * 16 + s;
            const float w = Wa[e * 2048 + d * 32 + hh];
            const unsigned int hb = f2b(w);
            Wafh[e * 2048 + i] = (unsigned short)hb;
            Wafl[e * 2048 + i] = (unsigned short)f2b(w - b2f(hb));
        }
    }
}

// ---- K2: scatter into sorted order (BASELINE VERBATIM) ----
__global__ void scatter_kernel(const int* __restrict__ eids, const int* __restrict__ etot,
                               const int* __restrict__ bbase, int* __restrict__ perm, int B) {
    __shared__ int lcnt[NE], esrt[NE], bb[NE];
    const int tid = threadIdx.x;
    if (tid < NE) { lcnt[tid] = 0; bb[tid] = bbase[blockIdx.x * NE + tid]; }
    if (tid == 0) {
        int es = 0;
        for (int e = 0; e < NE; ++e) { esrt[e] = es; es += etot[e]; }
    }
    __syncthreads();
    const int per = B / gridDim.x;
    const int blk = blockIdx.x * per;
    for (int i = tid; i < per; i += blockDim.x) {
        const int idx = blk + i;
        const int e = eids[idx];
        const int r = atomicAdd(&lcnt[e], 1);
        perm[esrt[e] + bb[e] + r] = idx;
    }
}

// ---- K3: fused MLP; layer2 + expert-A on MFMA (3-pass split-bf16) ----
// 64 threads = 1 wave = 64 samples; LDS 9216B; in-kernel etot scan.
// PROVEN: 56.3us in R17 structure, 55-56.5 across R10/R13.
__global__ __launch_bounds__(THREADS, 4) void wfc_kernel(
    const float* __restrict__ x, const int* __restrict__ perm,
    const int* __restrict__ etot,
    const float* __restrict__ W0, const float* __restrict__ b0,
    const bf16x8* __restrict__ W1fh, const bf16x8* __restrict__ W1fl,
    const float* __restrict__ b1,
    const bf16x8* __restrict__ Wafh, const bf16x8* __restrict__ Wafl,
    const float* __restrict__ ba,
    const float* __restrict__ Wb, const float* __restrict__ bb,
    float* __restrict__ out)
{
    __shared__ unsigned int sbuf[2304];      // max(32*SA, 64*SG) u32 = 9216 B

    // derive (eid, start, cnt): uniform scalar 30-iter scan (baseline-proven)
    int eid = -1, start = 0, cnt = 0;
    {
        int cum = 0, es = 0;
#pragma unroll 1
        for (int e = 0; e < NE; ++e) {
            const int t = etot[e];
            const int nb = (t + 63) >> 6;
            if ((int)blockIdx.x < cum + nb) {
                const int seg = blockIdx.x - cum;
                eid = e; start = es + (seg << 6); cnt = min(64, t - (seg << 6));
                break;
            }
            cum += nb; es += t;
        }
    }
    if (eid < 0) return;
    eid = __builtin_amdgcn_readfirstlane(eid);

    const int tid = threadIdx.x;
    const bool valid = tid < cnt;
    const int idx = perm[start + (valid ? tid : 0)];

    const int lane = tid & 63;
    const int wv   = tid >> 6;               // always 0 (1 wave); kept generic
    const int qd   = lane >> 4;
    const int l16  = lane & 15;

    const float x0 = x[idx * 3 + 0];
    const float x1 = x[idx * 3 + 1];
    const float x2 = x[idx * 3 + 2];

    // ---- layer 2 accumulators, init b1 (C layout: col = l16) ----
    f32x4 acc[4][4];
#pragma unroll
    for (int nt = 0; nt < 4; ++nt) {
        const float bv = b1[nt * 16 + l16];
#pragma unroll
        for (int mt = 0; mt < 4; ++mt) {
            f32x4 c; c[0] = bv; c[1] = bv; c[2] = bv; c[3] = bv;
            acc[mt][nt] = c;
        }
    }

    // ---- layer-2 GEMM: 4 K-chunks of 32 ----
    for (int c = 0; c < 4; ++c) {
        if (c) __syncthreads();
#pragma unroll
        for (int kk = 0; kk < 32; ++kk) {
            const int k = c * 32 + kk;
            const float pre = fmaf(x0, W0[k], fmaf(x1, W0[128 + k], fmaf(x2, W0[256 + k], b0[k])));
            sbuf[kk * SA + tid] = packsplit(fast_tanh(pre));
        }
        __syncthreads();

        bf16x8 Bhi[4], Blo[4];
#pragma unroll
        for (int nt = 0; nt < 4; ++nt) {
            const int rec = (c * 4 + nt) * 64 + qd * 16 + l16;
            Bhi[nt] = W1fh[rec];
            Blo[nt] = W1fl[rec];
        }
#pragma unroll
        for (int mt = 0; mt < 4; ++mt) {
            unsigned int a[8];
            const int mrow = wv * 64 + mt * 16 + l16;
#pragma unroll
            for (int j = 0; j < 8; ++j) a[j] = sbuf[(qd * 8 + j) * SA + mrow];
            bf16x8 Ahi, Alo;
            unpack8(a, Ahi, Alo);
#pragma unroll
            for (int nt = 0; nt < 4; ++nt) {
                acc[mt][nt] = __builtin_amdgcn_mfma_f32_16x16x32_bf16(Ahi, Bhi[nt], acc[mt][nt], 0, 0, 0);
                acc[mt][nt] = __builtin_amdgcn_mfma_f32_16x16x32_bf16(Ahi, Blo[nt], acc[mt][nt], 0, 0, 0);
                acc[mt][nt] = __builtin_amdgcn_mfma_f32_16x16x32_bf16(Alo, Bhi[nt], acc[mt][nt], 0, 0, 0);
            }
        }
    }

    // ---- expert-A accumulators, init ba ----
    f32x4 acc2[4][2];
#pragma unroll
    for (int nt2 = 0; nt2 < 2; ++nt2) {
        const float bv = ba[(eid << 5) + nt2 * 16 + l16];
#pragma unroll
        for (int mt = 0; mt < 4; ++mt) {
            f32x4 c; c[0] = bv; c[1] = bv; c[2] = bv; c[3] = bv;
            acc2[mt][nt2] = c;
        }
    }

    // ---- expert-A GEMM: h2 = tanh(acc) restaged [d][sample]; 2 K-chunks ----
    const bf16x8* __restrict__ waeh = Wafh + (eid << 8);
    const bf16x8* __restrict__ wael = Wafl + (eid << 8);
    for (int c2 = 0; c2 < 2; ++c2) {
        __syncthreads();
#pragma unroll
        for (int mt = 0; mt < 4; ++mt) {
#pragma unroll
            for (int ntl = 0; ntl < 2; ++ntl) {
#pragma unroll
                for (int r = 0; r < 4; ++r) {
                    const float h2 = fast_tanh(acc[mt][c2 * 2 + ntl][r]);
                    const int dl  = ntl * 16 + l16;
                    const int row = wv * 64 + mt * 16 + qd * 4 + r;
                    sbuf[dl * SA + row] = packsplit(h2);
                }
            }
        }
        __syncthreads();

        bf16x8 B2hi[2], B2lo[2];
#pragma unroll
        for (int nt2 = 0; nt2 < 2; ++nt2) {
            const int rec = (c2 * 2 + nt2) * 64 + qd * 16 + l16;
            B2hi[nt2] = waeh[rec];
            B2lo[nt2] = wael[rec];
        }
#pragma unroll
        for (int mt = 0; mt < 4; ++mt) {
            unsigned int a[8];
            const int mrow = wv * 64 + mt * 16 + l16;
#pragma unroll
            for (int j = 0; j < 8; ++j) a[j] = sbuf[(qd * 8 + j) * SA + mrow];
            bf16x8 Ahi, Alo;
            unpack8(a, Ahi, Alo);
#pragma unroll
            for (int nt2 = 0; nt2 < 2; ++nt2) {
                acc2[mt][nt2] = __builtin_amdgcn_mfma_f32_16x16x32_bf16(Ahi, B2hi[nt2], acc2[mt][nt2], 0, 0, 0);
                acc2[mt][nt2] = __builtin_amdgcn_mfma_f32_16x16x32_bf16(Ahi, B2lo[nt2], acc2[mt][nt2], 0, 0, 0);
                acc2[mt][nt2] = __builtin_amdgcn_mfma_f32_16x16x32_bf16(Alo, B2hi[nt2], acc2[mt][nt2], 0, 0, 0);
            }
        }
    }

    // ---- g = tanh(acc2) staged [sample][h], expert-B per-thread ----
    __syncthreads();
    float* g2 = (float*)sbuf;
#pragma unroll
    for (int mt = 0; mt < 4; ++mt) {
#pragma unroll
        for (int nt2 = 0; nt2 < 2; ++nt2) {
#pragma unroll
            for (int r = 0; r < 4; ++r) {
                const int row = wv * 64 + mt * 16 + qd * 4 + r;
                g2[row * SG + nt2 * 16 + l16] = fast_tanh(acc2[mt][nt2][r]);
            }
        }
    }
    __syncthreads();

    float gv[32];
    {
        const float4* grow = (const float4*)(g2 + tid * SG);
#pragma unroll
        for (int i = 0; i < 8; ++i) {
            float4 v = grow[i];
            gv[4 * i + 0] = v.x; gv[4 * i + 1] = v.y;
            gv[4 * i + 2] = v.z; gv[4 * i + 3] = v.w;
        }
    }

    const float* __restrict__ wbe = Wb + (eid << 6);
    float p0 = bb[2 * eid], p1 = bb[2 * eid + 1];
#pragma unroll
    for (int h = 0; h < 32; ++h) {
        p0 = fmaf(gv[h], wbe[2 * h + 0], p0);
        p1 = fmaf(gv[h], wbe[2 * h + 1], p1);
    }

    const float s = fmaf(p0, p0, fmaf(p1, p1, 1e-6f));
    const float inv = 1.0f / sqrtf(s);
    if (valid) {
        float2 o; o.x = p0 * inv; o.y = p1 * inv;
        ((float2*)out)[idx] = o;
    }
}

extern "C" void kernel_launch(void* const* d_in, const int* in_sizes, int n_in,
                              void* d_out, int out_size, void* d_ws, size_t ws_size,
                              hipStream_t stream) {
    const float* x  = (const float*)d_in[0];
    const int*   n  = (const int*)d_in[1];
    const int*   l  = (const int*)d_in[2];
    const int*   m  = (const int*)d_in[3];
    const float* W0 = (const float*)d_in[4];
    const float* b0 = (const float*)d_in[5];
    const float* W1 = (const float*)d_in[6];
    const float* b1 = (const float*)d_in[7];
    const float* Wa = (const float*)d_in[8];
    const float* ba = (const float*)d_in[9];
    const float* Wb = (const float*)d_in[10];
    const float* bb = (const float*)d_in[11];
    float* out = (float*)d_out;

    const int B = in_sizes[1];   // 262144

    // workspace layout (all segments 16B aligned) -- BASELINE VERBATIM
    int*            perm  = (int*)d_ws;                      // B
    int*            eids  = perm + B;                        // B
    int*            bbase = eids + B;                        // HB*NE = 3840
    int*            etot  = bbase + HB * NE;                 // 32
    unsigned short* W1fh  = (unsigned short*)(etot + 32);    // 8192 u16
    unsigned short* W1fl  = W1fh + 8192;                     // 8192 u16
    unsigned short* Wafh  = W1fl + 8192;                     // 30*2048 u16
    unsigned short* Wafl  = Wafh + NE * 2048;                // 30*2048 u16

    hipMemsetAsync(etot, 0, 32 * sizeof(int), stream);
    hist_pack_kernel<<<HB + 1 + NE, 256, 0, stream>>>(
        n, l, m, eids, etot, bbase, W1, W1fh, W1fl, Wa, Wafh, Wafl, B);
    scatter_kernel<<<HB, 256, 0, stream>>>(eids, etot, bbase, perm, B);
    wfc_kernel<<<MAXBLK, THREADS, 0, stream>>>(
        x, perm, etot, W0, b0,
        (const bf16x8*)W1fh, (const bf16x8*)W1fl, b1,
        (const bf16x8*)Wafh, (const bf16x8*)Wafl, ba, Wb, bb, out);
}